// Round 5
// baseline (7634.364 us; speedup 1.0000x reference)
//
#include <hip/hip_runtime.h>

typedef unsigned short u16;
typedef unsigned int u32;
typedef unsigned long long u64;
typedef __attribute__((ext_vector_type(8))) short short8;
typedef __attribute__((ext_vector_type(4))) float floatx4;
typedef __attribute__((ext_vector_type(4))) u32 u32x4;

#define B_   256
#define T_   512
#define E_   512
#define H_   1024
#define G4H  4096
#define KCAT 1536
#define M_   1024

__device__ __forceinline__ u16 f2bf(float f) {
    union { float f; unsigned u; } v; v.f = f;
    unsigned r = (v.u + 0x7fffu + ((v.u >> 16) & 1u)) >> 16;
    return (u16)r;
}
__device__ __forceinline__ float sigf(float x) {
    return __fdividef(1.0f, 1.0f + __expf(-x));
}
__device__ __forceinline__ float tanh_f(float x) {
    return 1.0f - __fdividef(2.0f, __expf(2.0f * x) + 1.0f);
}
// device-coherent 16B load / 2B store (bypass L1/L2 -> coherent at MALL)
__device__ __forceinline__ u32x4 load_sc(const u16* p) {
    u32x4 r;
    asm volatile("global_load_dwordx4 %0, %1, off sc0 sc1"
                 : "=v"(r) : "v"(p) : "memory");
    return r;
}
__device__ __forceinline__ void store_sc16(u16* p, u16 v) {
    asm volatile("global_store_short %0, %1, off sc0 sc1"
                 :: "v"(p), "v"((u32)v) : "memory");
}

// ---------------- prep kernels ----------------

// rank rows by x_index descending (stable): perm[rank]=orig, sxi[rank]=xi
__global__ void sort_rows(const int* __restrict__ x_index,
                          int* __restrict__ perm, int* __restrict__ sxi) {
    __shared__ int xl[B_];
    int tid = threadIdx.x;
    xl[tid] = x_index[tid];
    __syncthreads();
    int mine = xl[tid], rank = 0;
    for (int j = 0; j < B_; ++j)
        rank += (xl[j] > mine) || (xl[j] == mine && j < tid);
    perm[rank] = tid;
    sxi[rank] = mine;
}

// emb_bf[srow][t][e] = bf16(tab[x[perm[srow]][t]][e])
__global__ void prep_emb(const int* __restrict__ x, const float* __restrict__ tab,
                         const int* __restrict__ perm, u16* __restrict__ emb) {
    int idx = (blockIdx.x * 256 + threadIdx.x) * 4;   // [0, B*T*E)
    int srow = idx >> 18;                             // / (T*E)
    int t    = (idx >> 9) & 511;
    int e    = idx & 511;
    int orig = perm[srow];
    int xv   = x[orig * T_ + t];
    float4 v = *(const float4*)(tab + (size_t)xv * E_ + e);
    ushort4 o; o.x = f2bf(v.x); o.y = f2bf(v.y); o.z = f2bf(v.z); o.w = f2bf(v.w);
    *(ushort4*)(emb + idx) = o;
}

__global__ void prep_wcat(const float* __restrict__ Whh, const float* __restrict__ Wih,
                          u16* __restrict__ wcat) {
    int idx = (blockIdx.x * 256 + threadIdx.x) * 4;   // [0, 4096*1536)
    int g = idx / KCAT;
    int k = idx - g * KCAT;
    const float* src = (k < H_) ? (Whh + (size_t)g * H_ + k)
                                : (Wih + (size_t)g * E_ + (k - H_));
    float4 v = *(const float4*)src;
    ushort4 o; o.x = f2bf(v.x); o.y = f2bf(v.y); o.z = f2bf(v.z); o.w = f2bf(v.w);
    *(ushort4*)(wcat + idx) = o;
}

__global__ void prep_fc1w(const float* __restrict__ src, u16* __restrict__ dst) {
    int idx = (blockIdx.x * 256 + threadIdx.x) * 4;
    float4 v = *(const float4*)(src + idx);
    ushort4 o; o.x = f2bf(v.x); o.y = f2bf(v.y); o.z = f2bf(v.z); o.w = f2bf(v.w);
    *(ushort4*)(dst + idx) = o;
}

__global__ void prep_bias(const float* __restrict__ bih, const float* __restrict__ bhh,
                          float* __restrict__ bias) {
    int i = blockIdx.x * 256 + threadIdx.x;
    bias[i] = bih[i] + bhh[i];
}

// sorted h0 (bf16) and c0 (f32)
__global__ void prep_state(const float* __restrict__ h0, const float* __restrict__ c0,
                           const int* __restrict__ perm,
                           u16* __restrict__ hbuf0, float* __restrict__ c0p) {
    int i = blockIdx.x * 256 + threadIdx.x;           // [0, B*H)
    int srow = i >> 10, col = i & 1023;
    int orig = perm[srow];
    hbuf0[i] = f2bf(h0[(size_t)orig * H_ + col]);
    c0p[i]   = c0[(size_t)orig * H_ + col];
}

__global__ void zero_flags(u32* __restrict__ f) {
    f[blockIdx.x * 256 + threadIdx.x] = 0;            // [0, 8*128)
}

// ---------------- persistent LSTM ----------------
// 256 blocks x 256 threads (4 waves), 1 block/CU. grp = bid>>7 owns sorted rows
// [grp*128,+128); cb = bid&127 owns h-cols [8cb,8cb+8) (32 gate-cols i|f|g|o).
// Wave w owns 32 rows (2 MFMA row-frags). A-fragments load DIRECTLY from
// global (h: sc-coherent pipelined; emb: cached) -- no LDS staging. W lives in
// LDS in [ksub][col] fragment order (conflict-minimal contiguous wave reads).
// Epilogue is in-register via shfl_xor; gates->c->h without LDS.

__global__ __launch_bounds__(256) void lstm_persist(
    const u16* __restrict__ emb, const u16* __restrict__ wcat,
    const float* __restrict__ bias, const float* __restrict__ c0p,
    const int* __restrict__ sxi,
    u16* __restrict__ hbuf, float* __restrict__ hn, u32* __restrict__ flags)
{
    __shared__ __align__(16) u16 Wl[192 * 32 * 8];    // [ksub m][col][8] 98304 B

    const int tid  = threadIdx.x;
    const int w    = tid >> 6;        // wave 0..3
    const int lane = tid & 63;
    const int lr   = lane & 15;
    const int lk   = lane >> 4;
    const int grp  = blockIdx.x >> 7;
    const int cb   = blockIdx.x & 127;

    // ---- one-time: W -> LDS in fragment order ----
    for (int i = tid; i < 32 * 192; i += 256) {
        int col = i / 192, m = i - col * 192;
        int gcolw = (col >> 3) * H_ + cb * 8 + (col & 7);
        *(u32x4*)&Wl[(m * 32 + col) * 8] =
            *(const u32x4*)(wcat + (size_t)gcolw * KCAT + m * 8);
    }
    __syncthreads();   // the ONLY block barrier

    const int rowbase = grp * 128 + w * 32;
    const int j    = lr & 7;          // local h-col
    const int rsel = lr >> 3;         // which row pair of the quad
    const int r0   = lk * 4 + 2 * rsel;
    const int gcol = cb * 8 + j;
    const float bI = bias[gcol],        bF = bias[H_ + gcol];
    const float bG = bias[2 * H_ + gcol], bO = bias[3 * H_ + gcol];

    // c cells: (rt,0)=row rowbase+rt*16+r0, (rt,1)=+1
    float c00 = c0p[(size_t)(rowbase + r0) * H_ + gcol];
    float c01 = c0p[(size_t)(rowbase + r0 + 1) * H_ + gcol];
    float c10 = c0p[(size_t)(rowbase + 16 + r0) * H_ + gcol];
    float c11 = c0p[(size_t)(rowbase + 16 + r0 + 1) * H_ + gcol];
    const int xi00 = sxi[rowbase + r0],      xi01 = sxi[rowbase + r0 + 1];
    const int xi10 = sxi[rowbase + 16 + r0], xi11 = sxi[rowbase + 16 + r0 + 1];
    const int tmax = sxi[rowbase];    // sorted desc -> max xi of this 32-row tile

    for (int t = 0; t <= tmax; ++t) {
        const u16* hread  = hbuf + (size_t)(t & 1) * (B_ * H_);
        u16*       hwrite = hbuf + (size_t)((t + 1) & 1) * (B_ * H_);
        floatx4 a00 = {0.f,0.f,0.f,0.f}, a01 = {0.f,0.f,0.f,0.f};
        floatx4 a10 = {0.f,0.f,0.f,0.f}, a11 = {0.f,0.f,0.f,0.f};

        // ---- emb phase: K 1024..1536 (ksub m = 128..191), cached loads ----
        {
            const u16* e0p = emb + ((size_t)(rowbase + lr) * T_ + t) * E_ + lk * 8;
            const u16* e1p = e0p + (size_t)16 * T_ * E_;
            #pragma unroll
            for (int s = 0; s < 16; ++s) {
                short8 f0 = *(const short8*)(e0p + s * 32);
                short8 f1 = *(const short8*)(e1p + s * 32);
                short8 b0 = *(const short8*)&Wl[(((32 + s) * 4 + lk) * 32 + lr) * 8];
                short8 b1 = *(const short8*)&Wl[(((32 + s) * 4 + lk) * 32 + 16 + lr) * 8];
                a00 = __builtin_amdgcn_mfma_f32_16x16x32_bf16(f0, b0, a00, 0, 0, 0);
                a01 = __builtin_amdgcn_mfma_f32_16x16x32_bf16(f0, b1, a01, 0, 0, 0);
                a10 = __builtin_amdgcn_mfma_f32_16x16x32_bf16(f1, b0, a10, 0, 0, 0);
                a11 = __builtin_amdgcn_mfma_f32_16x16x32_bf16(f1, b1, a11, 0, 0, 0);
            }
        }

        // ---- wait for h_t: rows of tile w from all 128 blocks in group ----
        if (t > 0) {
            const u32* fp = flags + ((grp * 4 + w) << 7);
            while (true) {
                bool ok = true;
                if (lane < 32) {
                    u32x4 fv;
                    asm volatile("global_load_dwordx4 %0, %1, off sc0 sc1"
                                 : "=v"(fv) : "v"(fp + lane * 4) : "memory");
                    asm volatile("s_waitcnt vmcnt(0)" ::: "memory");
                    ok = fv.x >= (u32)t && fv.y >= (u32)t &&
                         fv.z >= (u32)t && fv.w >= (u32)t;
                }
                if (__all(ok)) break;
                __builtin_amdgcn_s_sleep(1);
            }
        }

        // ---- h phase: K 0..1024, direct-to-fragment sc loads, 16-deep ----
        {
            const u16* h0p = hread + (size_t)(rowbase + lr) * H_ + lk * 8;
            const u16* h1p = h0p + (size_t)16 * H_;
            u32x4 hv[16][2];
            #pragma unroll
            for (int s = 0; s < 16; ++s) {
                hv[s][0] = load_sc(h0p + s * 32);
                hv[s][1] = load_sc(h1p + s * 32);
            }
            #pragma unroll
            for (int s = 0; s < 32; ++s) {
                const int pend = (s < 16) ? 30 : (62 - 2 * s);
                asm volatile("s_waitcnt vmcnt(%0)" :: "i"(pend) : "memory");
                short8 f0 = *(short8*)&hv[s & 15][0];
                short8 f1 = *(short8*)&hv[s & 15][1];
                short8 b0 = *(const short8*)&Wl[((s * 4 + lk) * 32 + lr) * 8];
                short8 b1 = *(const short8*)&Wl[((s * 4 + lk) * 32 + 16 + lr) * 8];
                if (s < 16) {
                    hv[s][0] = load_sc(h0p + (s + 16) * 32);
                    hv[s][1] = load_sc(h1p + (s + 16) * 32);
                }
                a00 = __builtin_amdgcn_mfma_f32_16x16x32_bf16(f0, b0, a00, 0, 0, 0);
                a01 = __builtin_amdgcn_mfma_f32_16x16x32_bf16(f0, b1, a01, 0, 0, 0);
                a10 = __builtin_amdgcn_mfma_f32_16x16x32_bf16(f1, b0, a10, 0, 0, 0);
                a11 = __builtin_amdgcn_mfma_f32_16x16x32_bf16(f1, b1, a11, 0, 0, 0);
            }
        }

        // ---- in-register epilogue (shfl_xor gate combine), per row-tile ----
        auto epi = [&](const floatx4& aIH, const floatx4& aGO, int rowA,
                       float& cA, float& cB, int xiA, int xiB) {
            float u0 = __shfl_xor(rsel ? aIH[0] : aIH[2], 8);
            float u1 = __shfl_xor(rsel ? aIH[1] : aIH[3], 8);
            float v0 = __shfl_xor(rsel ? aGO[0] : aGO[2], 8);
            float v1 = __shfl_xor(rsel ? aGO[1] : aGO[3], 8);
            float gi0 = rsel ? u0 : aIH[0], gf0 = rsel ? aIH[2] : u0;
            float gi1 = rsel ? u1 : aIH[1], gf1 = rsel ? aIH[3] : u1;
            float gg0 = rsel ? v0 : aGO[0], go0 = rsel ? aGO[2] : v0;
            float gg1 = rsel ? v1 : aGO[1], go1 = rsel ? aGO[3] : v1;
            float i0 = sigf(gi0 + bI), f0 = sigf(gf0 + bF);
            float g0 = tanh_f(gg0 + bG), o0 = sigf(go0 + bO);
            float i1 = sigf(gi1 + bI), f1 = sigf(gf1 + bF);
            float g1 = tanh_f(gg1 + bG), o1 = sigf(go1 + bO);
            cA = f0 * cA + i0 * g0;
            cB = f1 * cB + i1 * g1;
            float hA = o0 * tanh_f(cA), hB = o1 * tanh_f(cB);
            store_sc16(hwrite + (size_t)rowA * H_ + gcol, f2bf(hA));
            store_sc16(hwrite + (size_t)(rowA + 1) * H_ + gcol, f2bf(hB));
            if (xiA == t) hn[(size_t)rowA * H_ + gcol] = hA;
            if (xiB == t) hn[(size_t)(rowA + 1) * H_ + gcol] = hB;
        };
        epi(a00, a01, rowbase + r0,      c00, c01, xi00, xi01);
        epi(a10, a11, rowbase + 16 + r0, c10, c11, xi10, xi11);

        asm volatile("s_waitcnt vmcnt(0)" ::: "memory");
        if (lane == 0)
            __hip_atomic_store(flags + ((grp * 4 + w) << 7) + cb, (u32)(t + 1),
                               __ATOMIC_RELAXED, __HIP_MEMORY_SCOPE_AGENT);
    }
}

// ---------------- tail ----------------

__global__ void hn_convert(const float* __restrict__ hn, u16* __restrict__ hnbf) {
    int i = blockIdx.x * 256 + threadIdx.x;
    hnbf[i] = f2bf(hn[i]);
}

__global__ __launch_bounds__(256) void fc1_kernel(
    const u16* __restrict__ A, const u16* __restrict__ Bw,
    const float* __restrict__ bvec, float* __restrict__ z)
{
    __shared__ __align__(16) u16 Als[64 * 72];
    __shared__ __align__(16) u16 Bls[64 * 72];
    const int tid = threadIdx.x;
    const int rowbase = blockIdx.y * 64;
    const int colbase = blockIdx.x * 64;
    floatx4 acc[4] = {{0,0,0,0},{0,0,0,0},{0,0,0,0},{0,0,0,0}};
    const int w = tid >> 6, lane = tid & 63, lr = lane & 15, lk = lane >> 4;

    for (int s = 0; s < H_ / 64; ++s) {
        int k0 = s * 64;
        #pragma unroll
        for (int cc2 = 0; cc2 < 2; ++cc2) {
            int c = tid + cc2 * 256;
            int row = c >> 3, kg = c & 7, kglob = k0 + kg * 8;
            *(u32x4*)&Als[(row * 9 + kg) * 8] =
                *(const u32x4*)(A + (size_t)(rowbase + row) * H_ + kglob);
            *(u32x4*)&Bls[(row * 9 + kg) * 8] =
                *(const u32x4*)(Bw + (size_t)(colbase + row) * H_ + kglob);
        }
        __syncthreads();
        #pragma unroll
        for (int ks = 0; ks < 2; ++ks) {
            short8 a = *(const short8*)&Als[((16 * w + lr) * 9 + ks * 4 + lk) * 8];
            #pragma unroll
            for (int q = 0; q < 4; ++q) {
                short8 b = *(const short8*)&Bls[((q * 16 + lr) * 9 + ks * 4 + lk) * 8];
                acc[q] = __builtin_amdgcn_mfma_f32_16x16x32_bf16(a, b, acc[q], 0, 0, 0);
            }
        }
        __syncthreads();
    }
    #pragma unroll
    for (int q = 0; q < 4; ++q) {
        int col = colbase + q * 16 + lr;
        float bb = bvec[col];
        #pragma unroll
        for (int r = 0; r < 4; ++r) {
            int row = rowbase + 16 * w + lk * 4 + r;
            z[(size_t)row * M_ + col] = tanh_f(acc[q][r] + bb);
        }
    }
}

__global__ __launch_bounds__(64) void fc2_softmax(
    const float* __restrict__ z, const float* __restrict__ wmat,
    const float* __restrict__ bvec, const int* __restrict__ perm,
    float* __restrict__ out)
{
    int bi = blockIdx.x;
    int lane = threadIdx.x;
    const float4* zr = (const float4*)(z + (size_t)bi * M_);
    const float4* w0 = (const float4*)(wmat);
    const float4* w1 = (const float4*)(wmat + M_);
    float s0 = 0.f, s1 = 0.f;
    for (int k = lane; k < M_ / 4; k += 64) {
        float4 zv = zr[k]; float4 a = w0[k]; float4 c = w1[k];
        s0 += zv.x * a.x + zv.y * a.y + zv.z * a.z + zv.w * a.w;
        s1 += zv.x * c.x + zv.y * c.y + zv.z * c.z + zv.w * c.w;
    }
    for (int off = 32; off; off >>= 1) {
        s0 += __shfl_down(s0, off);
        s1 += __shfl_down(s1, off);
    }
    if (lane == 0) {
        float l0 = s0 + bvec[0], l1 = s1 + bvec[1];
        float m = fmaxf(l0, l1);
        float lse = m + __logf(__expf(l0 - m) + __expf(l1 - m));
        int orig = perm[bi];
        out[orig * 2 + 0] = l0 - lse;
        out[orig * 2 + 1] = l1 - lse;
    }
}

// ---------------- launch ----------------

extern "C" void kernel_launch(void* const* d_in, const int* in_sizes, int n_in,
                              void* d_out, int out_size, void* d_ws, size_t ws_size,
                              hipStream_t stream)
{
    const int*   x       = (const int*)  d_in[0];
    const int*   x_index = (const int*)  d_in[1];
    const float* emb_t   = (const float*)d_in[2];
    const float* W_ih    = (const float*)d_in[3];
    const float* W_hh    = (const float*)d_in[4];
    const float* b_ih    = (const float*)d_in[5];
    const float* b_hh    = (const float*)d_in[6];
    const float* fc1_w   = (const float*)d_in[7];
    const float* fc1_b   = (const float*)d_in[8];
    const float* fc2_w   = (const float*)d_in[9];
    const float* fc2_b   = (const float*)d_in[10];
    const float* h0      = (const float*)d_in[11];
    const float* c0      = (const float*)d_in[12];
    float* out = (float*)d_out;

    char* p = (char*)d_ws;
    u16*   emb_bf = (u16*)p;   p += (size_t)B_ * T_ * E_ * 2;   // 134 MB
    u16*   wcat   = (u16*)p;   p += (size_t)G4H * KCAT * 2;     // 12.6 MB
    u16*   fc1wbf = (u16*)p;   p += (size_t)M_ * H_ * 2;        // 2 MB
    float* bias   = (float*)p; p += (size_t)G4H * 4;
    u16*   hbuf   = (u16*)p;   p += (size_t)2 * B_ * H_ * 2;    // ping-pong h
    float* c0p    = (float*)p; p += (size_t)B_ * H_ * 4;
    float* hn     = (float*)p; p += (size_t)B_ * H_ * 4;
    u16*   hnbf   = (u16*)p;   p += (size_t)B_ * H_ * 2;
    float* zbuf   = (float*)p; p += (size_t)B_ * M_ * 4;
    int*   perm   = (int*)p;   p += (size_t)B_ * 4;
    int*   sxi    = (int*)p;   p += (size_t)B_ * 4;
    u32*   flags  = (u32*)p;   p += (size_t)8 * 128 * 4;

    sort_rows <<<1,     256, 0, stream>>>(x_index, perm, sxi);
    prep_emb  <<<65536, 256, 0, stream>>>(x, emb_t, perm, emb_bf);
    prep_wcat <<<6144,  256, 0, stream>>>(W_hh, W_ih, wcat);
    prep_fc1w <<<1024,  256, 0, stream>>>(fc1_w, fc1wbf);
    prep_bias <<<16,    256, 0, stream>>>(b_ih, b_hh, bias);
    prep_state<<<1024,  256, 0, stream>>>(h0, c0, perm, hbuf, c0p);
    zero_flags<<<4,     256, 0, stream>>>(flags);

    lstm_persist<<<256, 256, 0, stream>>>(emb_bf, wcat, bias, c0p, sxi,
                                          hbuf, hn, flags);

    hn_convert <<<1024, 256, 0, stream>>>(hn, hnbf);
    fc1_kernel <<<dim3(16, 4), 256, 0, stream>>>(hnbf, fc1wbf, fc1_b, zbuf);
    fc2_softmax<<<256, 64, 0, stream>>>(zbuf, fc2_w, fc2_b, perm, out);
}